// Round 5
// baseline (791.029 us; speedup 1.0000x reference)
//
#include <hip/hip_runtime.h>
#include <hip/hip_bf16.h>

#define E_ 128
#define NSAMP 2048

typedef __attribute__((ext_vector_type(8))) short short8;
typedef __attribute__((ext_vector_type(4))) float floatx4;

__device__ __forceinline__ ushort f2b(float f) {
    union { __hip_bfloat16 h; ushort u; } cv;
    cv.h = __float2bfloat16(f);
    return cv.u;
}

__device__ __forceinline__ void gload_lds16(const ushort* g, ushort* l) {
    __builtin_amdgcn_global_load_lds(
        (const __attribute__((address_space(1))) void*)g,
        (__attribute__((address_space(3))) void*)l, 16, 0, 0);
}

// -------------------- h = ReLU(ids @ l1W^T + l1b), fp32 --------------------
__global__ void hyper_h(const float* __restrict__ input, const float* __restrict__ l1W,
                        const float* __restrict__ l1b, float* __restrict__ h)
{
    int b = blockIdx.x / 5;
    int o = (blockIdx.x % 5) * 256 + threadIdx.x;
    const float* ids = input + (size_t)b * 192 + 176;
    const float* w = l1W + (size_t)o * 16;
    float a = l1b[o];
#pragma unroll
    for (int i = 0; i < 16; i += 4) {
        float4 wv = *(const float4*)(w + i);
        a += ids[i] * wv.x + ids[i + 1] * wv.y + ids[i + 2] * wv.z + ids[i + 3] * wv.w;
    }
    h[(size_t)b * 1280 + o] = fmaxf(a, 0.f);
}

// -------------------- xT0[s][b] = input[b][s]  (s < 176), fp32 --------------------
__global__ void x0_t(const float* __restrict__ input, float* __restrict__ xT0)
{
    int idx = blockIdx.x * 256 + threadIdx.x;   // < 176*2048
    int s = idx >> 11, b = idx & 2047;
    xT0[idx] = input[(size_t)b * 192 + s];
}

// -------------------- fp32 -> bf16 convert (wW bulk) --------------------
__global__ void cvt_bf16(const float* __restrict__ src, ushort* __restrict__ dst, int n)
{
    int i = (blockIdx.x * 256 + threadIdx.x) * 8;
    if (i >= n) return;
    float4 a = *(const float4*)(src + i);
    float4 b = *(const float4*)(src + i + 4);
    union { ushort o[8]; uint4 v; } u;
    u.o[0] = f2b(a.x); u.o[1] = f2b(a.y); u.o[2] = f2b(a.z); u.o[3] = f2b(a.w);
    u.o[4] = f2b(b.x); u.o[5] = f2b(b.y); u.o[6] = f2b(b.z); u.o[7] = f2b(b.w);
    *(uint4*)(dst + i) = u.v;
}

// -------------------- build 3 virtual B-slices: [S]=bW rows, [S+1..S+2]=wb^T chunks --------
__global__ void cvt_bias(const float* __restrict__ bW, const float* __restrict__ wb,
                         ushort* __restrict__ dst, int S, int M)
{
    int idx = blockIdx.x * 256 + threadIdx.x;   // < 3*M*E_
    int slice = idx / (M * E_);
    int rem = idx - slice * (M * E_);
    int m = rem / E_, e = rem - m * E_;
    ushort v;
    if (slice == 0) {
        v = f2b(bW[(size_t)m * E_ + e]);
    } else {
        int s = (slice - 1) * 128 + e;
        v = (s < S) ? f2b(wb[(size_t)s * M + m]) : (ushort)0;
    }
    dst[(size_t)(S + slice) * M * E_ + rem] = v;
}

// ==================== big-layer GEMM (M=256): pipelined async LDS staging ====================
// BM=BN=128, 4 waves (2x2), BK=64 per phase, double-buffered LDS with ONE barrier/phase.
// Iter order: barrier (drains DMA issued one phase ago) -> issue DMA(ph+1) -> MFMA(ph)
// -> A-gen(ph+1). XOR-swizzled 16B groups (g' = g ^ (row&7)) keep all LDS ops <=2-way
// and lane-contiguous for global_load_lds.
__global__ __launch_bounds__(256, 2) void gemm_big(
    const ushort* __restrict__ wWb, const float* __restrict__ h,
    const float* __restrict__ xT, float* __restrict__ partial,
    int S, int iw, int ksplit, int btiles, int ntiles)
{
    __shared__ ushort As[2][128 * 64];
    __shared__ ushort Bs[2][128 * 64];

    const int tid = threadIdx.x;
    const int bt = blockIdx.x % btiles;
    const int nt = (blockIdx.x / btiles) % ntiles;
    const int ks = blockIdx.x / (btiles * ntiles);
    const int b0 = bt * 128;
    const int m0 = nt * 128;
    const int total_s = S + 3;
    const int base = total_s / ksplit;
    const int rem = total_s - base * ksplit;
    const int s0 = ks * base + min(ks, rem);
    const int s1 = s0 + base + (ks < rem ? 1 : 0);

    const int lane = tid & 63;
    const int wave = tid >> 6;
    const int quad = lane >> 4;
    const int lr = lane & 15;
    const int wm0 = (wave >> 1) * 64;
    const int wn0 = (wave & 1) * 64;

    const int tb = tid >> 3;            // A-gen row (0..31), +32*k2
    const int teg = tid & 7;            // A-gen e-group
    const int aswz = (teg ^ (tb & 7)) * 8;   // swizzled A slot (shorts)

    const int brow = lane >> 3;         // B-DMA local row (0..7)
    const int bgg = (lane & 7) ^ brow;  // global e-group for this lane's slot

    // preload h chunk (iw) fp32
    float hreg[4][2][8];
#pragma unroll
    for (int k2 = 0; k2 < 4; ++k2) {
#pragma unroll
        for (int p = 0; p < 2; ++p) {
            const float* src = h + (size_t)(b0 + tb + 32 * k2) * 1280 + (size_t)iw * E_ + p * 64 + teg * 8;
            float4 v0 = *(const float4*)(src);
            float4 v1 = *(const float4*)(src + 4);
            hreg[k2][p][0] = v0.x; hreg[k2][p][1] = v0.y; hreg[k2][p][2] = v0.z; hreg[k2][p][3] = v0.w;
            hreg[k2][p][4] = v1.x; hreg[k2][p][5] = v1.y; hreg[k2][p][6] = v1.z; hreg[k2][p][7] = v1.w;
        }
    }

    floatx4 acc[4][4];
#pragma unroll
    for (int i = 0; i < 4; ++i)
#pragma unroll
        for (int j = 0; j < 4; ++j)
            acc[i][j] = (floatx4){0.f, 0.f, 0.f, 0.f};

    float xv[4];

    auto dma_B = [&](int s, int p, int buf) {
#pragma unroll
        for (int t = 0; t < 4; ++t) {
            int rloc = wave * 32 + t * 8;
            const ushort* gp = wWb + ((size_t)s * 256 + m0 + rloc + brow) * E_ + p * 64 + bgg * 8;
            gload_lds16(gp, &Bs[buf][rloc * 64 + lane * 8]);
        }
    };

    auto gen_A = [&](int s, int p, int buf) {
        if (s < S) {
#pragma unroll
            for (int k2 = 0; k2 < 4; ++k2) {
                union { ushort o[8]; uint4 v; } u;
#pragma unroll
                for (int j = 0; j < 8; ++j) u.o[j] = f2b(xv[k2] * hreg[k2][p][j]);
                *(uint4*)&As[buf][(tb + 32 * k2) * 64 + aswz] = u.v;
            }
        } else if (s == S) {
#pragma unroll
            for (int k2 = 0; k2 < 4; ++k2) {
                const float* src = h + (size_t)(b0 + tb + 32 * k2) * 1280
                                     + (size_t)(iw + 1) * E_ + p * 64 + teg * 8;
                float4 v0 = *(const float4*)(src);
                float4 v1 = *(const float4*)(src + 4);
                union { ushort o[8]; uint4 v; } u;
                u.o[0] = f2b(v0.x); u.o[1] = f2b(v0.y); u.o[2] = f2b(v0.z); u.o[3] = f2b(v0.w);
                u.o[4] = f2b(v1.x); u.o[5] = f2b(v1.y); u.o[6] = f2b(v1.z); u.o[7] = f2b(v1.w);
                *(uint4*)&As[buf][(tb + 32 * k2) * 64 + aswz] = u.v;
            }
        } else {
            int j0 = (s - S - 1) * 128 + p * 64 + teg * 8;
#pragma unroll
            for (int k2 = 0; k2 < 4; ++k2) {
                int b = b0 + tb + 32 * k2;
                union { ushort o[8]; uint4 v; } u;
#pragma unroll
                for (int jj = 0; jj < 8; ++jj) {
                    int sp = j0 + jj;
                    u.o[jj] = (sp < S) ? f2b(xT[(size_t)sp * NSAMP + b]) : (ushort)0;
                }
                *(uint4*)&As[buf][(tb + 32 * k2) * 64 + aswz] = u.v;
            }
        }
    };

    const int nph = (s1 - s0) * 2;

    // ---- prologue: stage phase 0 into buf 0 ----
    if (s0 < S) {
#pragma unroll
        for (int k2 = 0; k2 < 4; ++k2)
            xv[k2] = xT[(size_t)s0 * NSAMP + b0 + tb + 32 * k2];
    }
    dma_B(s0, 0, 0);
    gen_A(s0, 0, 0);

    for (int ph = 0; ph < nph; ++ph) {
        const int cur = ph & 1;
        const int np = ph + 1;
        const int sn = s0 + (np >> 1);
        const int pn = np & 1;
        const bool stage = np < nph;

        __syncthreads();   // buf[cur] fully staged (DMA drained), prev reads of buf[cur^1] done

        if (stage) dma_B(sn, pn, cur ^ 1);

        // prefetch next slice's x values (issued before MFMA so latency hides)
        float xvn[4];
        const bool newx = stage && pn == 0 && sn < S;
        if (newx) {
#pragma unroll
            for (int k2 = 0; k2 < 4; ++k2)
                xvn[k2] = xT[(size_t)sn * NSAMP + b0 + tb + 32 * k2];
        }

        // ---- MFMA on buf[cur] ----
#pragma unroll
        for (int kk = 0; kk < 2; ++kk) {
            const int swz = ((kk * 4 + quad) ^ (lr & 7)) * 8;
            short8 af[4], bfr[4];
#pragma unroll
            for (int i = 0; i < 4; ++i)
                af[i] = *(const short8*)&As[cur][(wm0 + i * 16 + lr) * 64 + swz];
#pragma unroll
            for (int j = 0; j < 4; ++j)
                bfr[j] = *(const short8*)&Bs[cur][(wn0 + j * 16 + lr) * 64 + swz];
#pragma unroll
            for (int i = 0; i < 4; ++i)
#pragma unroll
                for (int j = 0; j < 4; ++j)
                    acc[i][j] = __builtin_amdgcn_mfma_f32_16x16x32_bf16(af[i], bfr[j], acc[i][j], 0, 0, 0);
        }

        // ---- A-gen for next phase into buf^1 ----
        if (stage) {
            if (newx) {
#pragma unroll
                for (int k2 = 0; k2 < 4; ++k2) xv[k2] = xvn[k2];
            }
            gen_A(sn, pn, cur ^ 1);
        }
    }

    // epilogue: C/D layout col=lane&15, row=quad*4+r
    float* dst = partial + (size_t)ks * NSAMP * 256;
#pragma unroll
    for (int i = 0; i < 4; ++i)
#pragma unroll
        for (int j = 0; j < 4; ++j)
#pragma unroll
            for (int r = 0; r < 4; ++r) {
                int row = wm0 + i * 16 + quad * 4 + r;
                int col = wn0 + j * 16 + lr;
                dst[(size_t)(b0 + row) * 256 + m0 + col] = acc[i][j][r];
            }
}

// ==================== small-layer GEMM (M=16) — previous structure ====================
template<int BM, int BN, int WROWS, int WCOLS>
__global__ __launch_bounds__(256, 2) void gemm_k(
    const ushort* __restrict__ wWb, const float* __restrict__ h,
    const float* __restrict__ xT, float* __restrict__ partial,
    int S, int M, int iw, int ksplit, int btiles, int ntiles)
{
    constexpr int SM = BM / WROWS / 16;
    constexpr int SN = BN / WCOLS / 16;
    constexpr int ASLOTS = BM * 8 / 256;
    constexpr int LDA = 72;

    __shared__ ushort As[BM][LDA];
    __shared__ ushort Bs[BN][LDA];

    const int tid = threadIdx.x;
    const int bt = blockIdx.x % btiles;
    const int nt = (blockIdx.x / btiles) % ntiles;
    const int ks = blockIdx.x / (btiles * ntiles);
    const int b0 = bt * BM;
    const int m0 = nt * BN;
    const int total_s = S + 3;
    const int base = total_s / ksplit;
    const int rem = total_s - base * ksplit;
    const int s0 = ks * base + min(ks, rem);
    const int s1 = s0 + base + (ks < rem ? 1 : 0);

    const int lane = tid & 63;
    const int wave = tid >> 6;
    const int quad = lane >> 4;
    const int lr = lane & 15;
    const int wm0 = (wave / WCOLS) * (BM / WROWS);
    const int wn0 = (wave % WCOLS) * (BN / WCOLS);

    const int tb = tid >> 3;
    const int teg = tid & 7;

    float hreg[ASLOTS][2][8];
#pragma unroll
    for (int k2 = 0; k2 < ASLOTS; ++k2) {
        int b = tb + 32 * k2;
#pragma unroll
        for (int p = 0; p < 2; ++p) {
            const float* src = h + (size_t)(b0 + b) * 1280 + (size_t)iw * E_ + p * 64 + teg * 8;
            float4 v0 = *(const float4*)(src);
            float4 v1 = *(const float4*)(src + 4);
            hreg[k2][p][0] = v0.x; hreg[k2][p][1] = v0.y; hreg[k2][p][2] = v0.z; hreg[k2][p][3] = v0.w;
            hreg[k2][p][4] = v1.x; hreg[k2][p][5] = v1.y; hreg[k2][p][6] = v1.z; hreg[k2][p][7] = v1.w;
        }
    }

    floatx4 acc[SM][SN];
#pragma unroll
    for (int i = 0; i < SM; ++i)
#pragma unroll
        for (int j = 0; j < SN; ++j)
            acc[i][j] = (floatx4){0.f, 0.f, 0.f, 0.f};

    for (int s = s0; s < s1; ++s) {
        float xv[ASLOTS];
        if (s < S) {
#pragma unroll
            for (int k2 = 0; k2 < ASLOTS; ++k2)
                xv[k2] = xT[(size_t)s * NSAMP + b0 + tb + 32 * k2];
        }

#pragma unroll
        for (int p = 0; p < 2; ++p) {
            if (s < S) {
#pragma unroll
                for (int k2 = 0; k2 < ASLOTS; ++k2) {
                    union { ushort o[8]; uint4 v; } u;
#pragma unroll
                    for (int j = 0; j < 8; ++j) u.o[j] = f2b(xv[k2] * hreg[k2][p][j]);
                    *(uint4*)&As[tb + 32 * k2][teg * 8] = u.v;
                }
            } else if (s == S) {
#pragma unroll
                for (int k2 = 0; k2 < ASLOTS; ++k2) {
                    const float* src = h + (size_t)(b0 + tb + 32 * k2) * 1280
                                         + (size_t)(iw + 1) * E_ + p * 64 + teg * 8;
                    float4 v0 = *(const float4*)(src);
                    float4 v1 = *(const float4*)(src + 4);
                    union { ushort o[8]; uint4 v; } u;
                    u.o[0] = f2b(v0.x); u.o[1] = f2b(v0.y); u.o[2] = f2b(v0.z); u.o[3] = f2b(v0.w);
                    u.o[4] = f2b(v1.x); u.o[5] = f2b(v1.y); u.o[6] = f2b(v1.z); u.o[7] = f2b(v1.w);
                    *(uint4*)&As[tb + 32 * k2][teg * 8] = u.v;
                }
            } else {
                int j0 = (s - S - 1) * 128 + p * 64 + teg * 8;
#pragma unroll
                for (int k2 = 0; k2 < ASLOTS; ++k2) {
                    int b = b0 + tb + 32 * k2;
                    union { ushort o[8]; uint4 v; } u;
#pragma unroll
                    for (int jj = 0; jj < 8; ++jj) {
                        int sp = j0 + jj;
                        u.o[jj] = (sp < S) ? f2b(xT[(size_t)sp * NSAMP + b]) : (ushort)0;
                    }
                    *(uint4*)&As[tb + 32 * k2][teg * 8] = u.v;
                }
            }
#pragma unroll
            for (int slot = tid; slot < BN * 8; slot += 256) {
                int m = slot >> 3, eg2 = slot & 7;
                *(uint4*)&Bs[m][eg2 * 8] =
                    *(const uint4*)(wWb + ((size_t)s * M + m0 + m) * E_ + p * 64 + eg2 * 8);
            }
            __syncthreads();
#pragma unroll
            for (int kk = 0; kk < 2; ++kk) {
                short8 af[SM], bfr[SN];
#pragma unroll
                for (int i = 0; i < SM; ++i)
                    af[i] = *(const short8*)&As[wm0 + i * 16 + lr][kk * 32 + quad * 8];
#pragma unroll
                for (int j = 0; j < SN; ++j)
                    bfr[j] = *(const short8*)&Bs[wn0 + j * 16 + lr][kk * 32 + quad * 8];
#pragma unroll
                for (int i = 0; i < SM; ++i)
#pragma unroll
                    for (int j = 0; j < SN; ++j)
                        acc[i][j] = __builtin_amdgcn_mfma_f32_16x16x32_bf16(af[i], bfr[j], acc[i][j], 0, 0, 0);
            }
            __syncthreads();
        }
    }

    float* dst = partial + (size_t)ks * NSAMP * M;
#pragma unroll
    for (int i = 0; i < SM; ++i)
#pragma unroll
        for (int j = 0; j < SN; ++j)
#pragma unroll
            for (int r = 0; r < 4; ++r) {
                int row = wm0 + i * 16 + quad * 4 + r;
                int col = wn0 + j * 16 + lr;
                dst[(size_t)(b0 + row) * M + m0 + col] = acc[i][j][r];
            }
}

// -------------------- reduce partials + bb (+ReLU), emit xT fp32 for next layer --------------
__global__ void reduce_mid(const float* __restrict__ partial, const float* __restrict__ bb,
                           float* __restrict__ xTn, int KS, int relu)
{
    __shared__ float t[32][33];
    const int b0 = (blockIdx.x >> 3) * 32;
    const int m0 = (blockIdx.x & 7) * 32;
    const int mo = threadIdx.x & 31;
    const int bs0 = threadIdx.x >> 5;   // 0..7
    const float bv = bb[m0 + mo];
#pragma unroll
    for (int r = 0; r < 4; ++r) {
        const int bs = bs0 + 8 * r;
        const size_t off = (size_t)(b0 + bs) * 256 + m0 + mo;
        float a0 = 0.f, a1 = 0.f, a2 = 0.f, a3 = 0.f;
#pragma unroll
        for (int k = 0; k < 16; k += 4) {
            a0 += partial[(size_t)(k + 0) * (NSAMP * 256) + off];
            a1 += partial[(size_t)(k + 1) * (NSAMP * 256) + off];
            a2 += partial[(size_t)(k + 2) * (NSAMP * 256) + off];
            a3 += partial[(size_t)(k + 3) * (NSAMP * 256) + off];
        }
        float a = (a0 + a1) + (a2 + a3) + bv;
        if (relu) a = fmaxf(a, 0.f);
        t[bs][mo] = a;
    }
    __syncthreads();
    const int bo = threadIdx.x & 31;
    const int ms0 = threadIdx.x >> 5;
#pragma unroll
    for (int r = 0; r < 4; ++r) {
        const int ms = ms0 + 8 * r;
        xTn[(size_t)(m0 + ms) * NSAMP + b0 + bo] = t[bo][ms];
    }
}

// -------------------- final layer reduce -> d_out (fp32, ReLU) --------------------
__global__ void reduce_out(const float* __restrict__ partial, const float* __restrict__ bb,
                           float* __restrict__ out, int KS)
{
    int idx = blockIdx.x * 256 + threadIdx.x;   // < 2048*16
    float a0 = 0.f, a1 = 0.f, a2 = 0.f, a3 = 0.f;
#pragma unroll
    for (int k = 0; k < 32; k += 4) {
        a0 += partial[(size_t)(k + 0) * (NSAMP * 16) + idx];
        a1 += partial[(size_t)(k + 1) * (NSAMP * 16) + idx];
        a2 += partial[(size_t)(k + 2) * (NSAMP * 16) + idx];
        a3 += partial[(size_t)(k + 3) * (NSAMP * 16) + idx];
    }
    out[idx] = fmaxf((a0 + a1) + (a2 + a3) + bb[idx & 15], 0.f);
}

extern "C" void kernel_launch(void* const* d_in, const int* in_sizes, int n_in,
                              void* d_out, int out_size, void* d_ws, size_t ws_size,
                              hipStream_t stream)
{
    const float* input = (const float*)d_in[0];
    const float* l1W   = (const float*)d_in[1];
    const float* l1b   = (const float*)d_in[2];

    char* ws = (char*)d_ws;
    // layout (bytes): wWb 16.98M | h 10.49M | xT0 2M | xT1 2M | partial 33.55M = 65.2MB
    ushort* wWb = (ushort*)(ws + 0);
    float* h    = (float*)(ws + 16975872);
    float* xT0  = (float*)(ws + 27461632);
    float* xT1  = (float*)(ws + 29558784);
    float* part = (float*)(ws + 31655936);

    hipLaunchKernelGGL(hyper_h, dim3(2048 * 5), dim3(256), 0, stream, input, l1W, l1b, h);
    hipLaunchKernelGGL(x0_t, dim3(176 * 2048 / 256), dim3(256), 0, stream, input, xT0);

    const int S_[5] = {176, 256, 256, 256, 256};
    const int M_[5] = {256, 256, 256, 256, 16};
    float* xt[2] = {xT0, xT1};

    for (int i = 0; i < 5; ++i) {
        const float* wW = (const float*)d_in[3 + 4 * i];
        const float* wb = (const float*)d_in[4 + 4 * i];
        const float* bW = (const float*)d_in[5 + 4 * i];
        const float* bb = (const float*)d_in[6 + 4 * i];
        float* xin = xt[i & 1];
        int n = S_[i] * M_[i] * E_;
        hipLaunchKernelGGL(cvt_bf16, dim3(n / 2048), dim3(256), 0, stream, wW, wWb, n);
        hipLaunchKernelGGL(cvt_bias, dim3(3 * M_[i] * E_ / 256), dim3(256), 0, stream,
                           bW, wb, wWb, S_[i], M_[i]);

        if (M_[i] == 256) {
            const int btiles = 16, ntiles = 2, ksplit = 16;
            hipLaunchKernelGGL(gemm_big, dim3(btiles * ntiles * ksplit), dim3(256), 0, stream,
                               wWb, h, xin, part, S_[i], 2 * i, ksplit, btiles, ntiles);
            hipLaunchKernelGGL(reduce_mid, dim3(512), dim3(256), 0, stream,
                               part, bb, xt[(i + 1) & 1], ksplit, (i < 3) ? 1 : 0);
        } else {
            const int btiles = 8, ntiles = 1, ksplit = 32;
            hipLaunchKernelGGL((gemm_k<256, 16, 4, 1>), dim3(btiles * ntiles * ksplit), dim3(256), 0, stream,
                               wWb, h, xin, part, S_[i], 16, 2 * i, ksplit, btiles, ntiles);
            hipLaunchKernelGGL(reduce_out, dim3(128), dim3(256), 0, stream,
                               part, bb, (float*)d_out, ksplit);
        }
    }
}

// Round 6
// 659.829 us; speedup vs baseline: 1.1988x; 1.1988x over previous
//
#include <hip/hip_runtime.h>
#include <hip/hip_bf16.h>

#define E_ 128
#define NSAMP 2048

typedef __attribute__((ext_vector_type(8))) short short8;
typedef __attribute__((ext_vector_type(4))) float floatx4;

__device__ __forceinline__ ushort f2b(float f) {
    union { __hip_bfloat16 h; ushort u; } cv;
    cv.h = __float2bfloat16(f);
    return cv.u;
}

__device__ __forceinline__ void gload_lds16(const ushort* g, ushort* l) {
    __builtin_amdgcn_global_load_lds(
        (const __attribute__((address_space(1))) void*)g,
        (__attribute__((address_space(3))) void*)l, 16, 0, 0);
}

// -------------------- h = ReLU(ids @ l1W^T + l1b), fp32 --------------------
__global__ void hyper_h(const float* __restrict__ input, const float* __restrict__ l1W,
                        const float* __restrict__ l1b, float* __restrict__ h)
{
    int b = blockIdx.x / 5;
    int o = (blockIdx.x % 5) * 256 + threadIdx.x;
    const float* ids = input + (size_t)b * 192 + 176;
    const float* w = l1W + (size_t)o * 16;
    float a = l1b[o];
#pragma unroll
    for (int i = 0; i < 16; i += 4) {
        float4 wv = *(const float4*)(w + i);
        a += ids[i] * wv.x + ids[i + 1] * wv.y + ids[i + 2] * wv.z + ids[i + 3] * wv.w;
    }
    h[(size_t)b * 1280 + o] = fmaxf(a, 0.f);
}

// -------------------- xT0[s][b] = input[b][s]  (s < 176), fp32 --------------------
__global__ void x0_t(const float* __restrict__ input, float* __restrict__ xT0)
{
    int idx = blockIdx.x * 256 + threadIdx.x;   // < 176*2048
    int s = idx >> 11, b = idx & 2047;
    xT0[idx] = input[(size_t)b * 192 + s];
}

// -------------------- fp32 -> bf16 convert (wW bulk) --------------------
__global__ void cvt_bf16(const float* __restrict__ src, ushort* __restrict__ dst, int n)
{
    int i = (blockIdx.x * 256 + threadIdx.x) * 8;
    if (i >= n) return;
    float4 a = *(const float4*)(src + i);
    float4 b = *(const float4*)(src + i + 4);
    union { ushort o[8]; uint4 v; } u;
    u.o[0] = f2b(a.x); u.o[1] = f2b(a.y); u.o[2] = f2b(a.z); u.o[3] = f2b(a.w);
    u.o[4] = f2b(b.x); u.o[5] = f2b(b.y); u.o[6] = f2b(b.z); u.o[7] = f2b(b.w);
    *(uint4*)(dst + i) = u.v;
}

// -------------------- build 3 virtual B-slices: [S]=bW rows, [S+1..S+2]=wb^T chunks --------
__global__ void cvt_bias(const float* __restrict__ bW, const float* __restrict__ wb,
                         ushort* __restrict__ dst, int S, int M)
{
    int idx = blockIdx.x * 256 + threadIdx.x;   // < 3*M*E_
    int slice = idx / (M * E_);
    int rem = idx - slice * (M * E_);
    int m = rem / E_, e = rem - m * E_;
    ushort v;
    if (slice == 0) {
        v = f2b(bW[(size_t)m * E_ + e]);
    } else {
        int s = (slice - 1) * 128 + e;
        v = (s < S) ? f2b(wb[(size_t)s * M + m]) : (ushort)0;
    }
    dst[(size_t)(S + slice) * M * E_ + rem] = v;
}

// ==================== big-layer GEMM (M=256): R4 structure + 4 blocks/CU ====================
// BM=128, BN=64, 4 waves (2x2, wave tile 64x32), BK=64/phase, 24KB LDS.
// Per phase: barrier -> issue B-DMA (async, global_load_lds w16) -> A-gen (x*h, direct h
// loads — L1/L2-hit, no hreg cache so VGPR fits 4 waves/SIMD) -> barrier -> MFMA.
// XOR swizzle (g' = g ^ (row&7)) keeps every LDS op <=2-way and DMA lane-contiguous.
__global__ __launch_bounds__(256, 4) void gemm_big(
    const ushort* __restrict__ wWb, const float* __restrict__ h,
    const float* __restrict__ xT, float* __restrict__ partial,
    int S, int iw, int ksplit, int btiles, int ntiles)
{
    __shared__ ushort As[128 * 64];
    __shared__ ushort Bs[64 * 64];

    const int tid = threadIdx.x;
    const int bt = blockIdx.x % btiles;
    const int nt = (blockIdx.x / btiles) % ntiles;
    const int ks = blockIdx.x / (btiles * ntiles);
    const int b0 = bt * 128;
    const int m0 = nt * 64;
    const int total_s = S + 3;
    const int base = total_s / ksplit;
    const int rem = total_s - base * ksplit;
    const int s0 = ks * base + min(ks, rem);
    const int s1 = s0 + base + (ks < rem ? 1 : 0);

    const int lane = tid & 63;
    const int wave = tid >> 6;
    const int quad = lane >> 4;
    const int lr = lane & 15;
    const int wm0 = (wave >> 1) * 64;   // wave m-offset (0/64)
    const int wn0 = (wave & 1) * 32;    // wave n-offset (0/32)

    const int tb = tid >> 3;            // A-gen row (0..31), +32*k2
    const int teg = tid & 7;            // A-gen e-group
    const int aswz = (teg ^ (tb & 7)) * 8;

    const int brow = lane >> 3;         // B-DMA row within 8-row slab
    const int bgg = (lane & 7) ^ brow;  // global e-group for this lane's swizzled slot

    floatx4 acc[4][2];
#pragma unroll
    for (int i = 0; i < 4; ++i)
#pragma unroll
        for (int j = 0; j < 2; ++j)
            acc[i][j] = (floatx4){0.f, 0.f, 0.f, 0.f};

    for (int s = s0; s < s1; ++s) {
        float xv[4];
        if (s < S) {
#pragma unroll
            for (int k2 = 0; k2 < 4; ++k2)
                xv[k2] = xT[(size_t)s * NSAMP + b0 + tb + 32 * k2];
        }

#pragma unroll
        for (int p = 0; p < 2; ++p) {
            __syncthreads();   // previous phase's frag reads complete

            // ---- B: async global->LDS DMA (64 rows; 2 slabs of 8 rows per wave) ----
#pragma unroll
            for (int t = 0; t < 2; ++t) {
                int rloc = wave * 16 + t * 8;
                const ushort* gp = wWb + ((size_t)s * 256 + m0 + rloc + brow) * E_ + p * 64 + bgg * 8;
                gload_lds16(gp, &Bs[rloc * 64 + lane * 8]);
            }

            // ---- A: generate and stage (h read directly; L1/L2-resident) ----
            if (s < S) {
#pragma unroll
                for (int k2 = 0; k2 < 4; ++k2) {
                    const float* src = h + (size_t)(b0 + tb + 32 * k2) * 1280
                                         + (size_t)iw * E_ + p * 64 + teg * 8;
                    float4 v0 = *(const float4*)(src);
                    float4 v1 = *(const float4*)(src + 4);
                    union { ushort o[8]; uint4 v; } u;
                    u.o[0] = f2b(xv[k2] * v0.x); u.o[1] = f2b(xv[k2] * v0.y);
                    u.o[2] = f2b(xv[k2] * v0.z); u.o[3] = f2b(xv[k2] * v0.w);
                    u.o[4] = f2b(xv[k2] * v1.x); u.o[5] = f2b(xv[k2] * v1.y);
                    u.o[6] = f2b(xv[k2] * v1.z); u.o[7] = f2b(xv[k2] * v1.w);
                    *(uint4*)&As[(tb + 32 * k2) * 64 + aswz] = u.v;
                }
            } else if (s == S) {
#pragma unroll
                for (int k2 = 0; k2 < 4; ++k2) {
                    const float* src = h + (size_t)(b0 + tb + 32 * k2) * 1280
                                         + (size_t)(iw + 1) * E_ + p * 64 + teg * 8;
                    float4 v0 = *(const float4*)(src);
                    float4 v1 = *(const float4*)(src + 4);
                    union { ushort o[8]; uint4 v; } u;
                    u.o[0] = f2b(v0.x); u.o[1] = f2b(v0.y); u.o[2] = f2b(v0.z); u.o[3] = f2b(v0.w);
                    u.o[4] = f2b(v1.x); u.o[5] = f2b(v1.y); u.o[6] = f2b(v1.z); u.o[7] = f2b(v1.w);
                    *(uint4*)&As[(tb + 32 * k2) * 64 + aswz] = u.v;
                }
            } else {
                int j0 = (s - S - 1) * 128 + p * 64 + teg * 8;
#pragma unroll
                for (int k2 = 0; k2 < 4; ++k2) {
                    int b = b0 + tb + 32 * k2;
                    union { ushort o[8]; uint4 v; } u;
#pragma unroll
                    for (int jj = 0; jj < 8; ++jj) {
                        int sp = j0 + jj;
                        u.o[jj] = (sp < S) ? f2b(xT[(size_t)sp * NSAMP + b]) : (ushort)0;
                    }
                    *(uint4*)&As[(tb + 32 * k2) * 64 + aswz] = u.v;
                }
            }

            __syncthreads();   // staging (incl. DMA via vmcnt drain) visible

            // ---- MFMA on this phase ----
#pragma unroll
            for (int kk = 0; kk < 2; ++kk) {
                const int swz = ((kk * 4 + quad) ^ (lr & 7)) * 8;
                short8 af[4], bfr[2];
#pragma unroll
                for (int i = 0; i < 4; ++i)
                    af[i] = *(const short8*)&As[(wm0 + i * 16 + lr) * 64 + swz];
#pragma unroll
                for (int j = 0; j < 2; ++j)
                    bfr[j] = *(const short8*)&Bs[(wn0 + j * 16 + lr) * 64 + swz];
#pragma unroll
                for (int i = 0; i < 4; ++i)
#pragma unroll
                    for (int j = 0; j < 2; ++j)
                        acc[i][j] = __builtin_amdgcn_mfma_f32_16x16x32_bf16(af[i], bfr[j], acc[i][j], 0, 0, 0);
            }
        }
    }

    // epilogue: C/D layout col=lane&15, row=quad*4+r
    float* dst = partial + (size_t)ks * NSAMP * 256;
#pragma unroll
    for (int i = 0; i < 4; ++i)
#pragma unroll
        for (int j = 0; j < 2; ++j)
#pragma unroll
            for (int r = 0; r < 4; ++r) {
                int row = wm0 + i * 16 + quad * 4 + r;
                int col = m0 + wn0 + j * 16 + lr;
                dst[(size_t)(b0 + row) * 256 + col] = acc[i][j][r];
            }
}

// ==================== small-layer GEMM (M=16) — unchanged ====================
template<int BM, int BN, int WROWS, int WCOLS>
__global__ __launch_bounds__(256, 2) void gemm_k(
    const ushort* __restrict__ wWb, const float* __restrict__ h,
    const float* __restrict__ xT, float* __restrict__ partial,
    int S, int M, int iw, int ksplit, int btiles, int ntiles)
{
    constexpr int SM = BM / WROWS / 16;
    constexpr int SN = BN / WCOLS / 16;
    constexpr int ASLOTS = BM * 8 / 256;
    constexpr int LDA = 72;

    __shared__ ushort As[BM][LDA];
    __shared__ ushort Bs[BN][LDA];

    const int tid = threadIdx.x;
    const int bt = blockIdx.x % btiles;
    const int nt = (blockIdx.x / btiles) % ntiles;
    const int ks = blockIdx.x / (btiles * ntiles);
    const int b0 = bt * BM;
    const int m0 = nt * BN;
    const int total_s = S + 3;
    const int base = total_s / ksplit;
    const int rem = total_s - base * ksplit;
    const int s0 = ks * base + min(ks, rem);
    const int s1 = s0 + base + (ks < rem ? 1 : 0);

    const int lane = tid & 63;
    const int wave = tid >> 6;
    const int quad = lane >> 4;
    const int lr = lane & 15;
    const int wm0 = (wave / WCOLS) * (BM / WROWS);
    const int wn0 = (wave % WCOLS) * (BN / WCOLS);

    const int tb = tid >> 3;
    const int teg = tid & 7;

    float hreg[ASLOTS][2][8];
#pragma unroll
    for (int k2 = 0; k2 < ASLOTS; ++k2) {
        int b = tb + 32 * k2;
#pragma unroll
        for (int p = 0; p < 2; ++p) {
            const float* src = h + (size_t)(b0 + b) * 1280 + (size_t)iw * E_ + p * 64 + teg * 8;
            float4 v0 = *(const float4*)(src);
            float4 v1 = *(const float4*)(src + 4);
            hreg[k2][p][0] = v0.x; hreg[k2][p][1] = v0.y; hreg[k2][p][2] = v0.z; hreg[k2][p][3] = v0.w;
            hreg[k2][p][4] = v1.x; hreg[k2][p][5] = v1.y; hreg[k2][p][6] = v1.z; hreg[k2][p][7] = v1.w;
        }
    }

    floatx4 acc[SM][SN];
#pragma unroll
    for (int i = 0; i < SM; ++i)
#pragma unroll
        for (int j = 0; j < SN; ++j)
            acc[i][j] = (floatx4){0.f, 0.f, 0.f, 0.f};

    for (int s = s0; s < s1; ++s) {
        float xv[ASLOTS];
        if (s < S) {
#pragma unroll
            for (int k2 = 0; k2 < ASLOTS; ++k2)
                xv[k2] = xT[(size_t)s * NSAMP + b0 + tb + 32 * k2];
        }

#pragma unroll
        for (int p = 0; p < 2; ++p) {
            if (s < S) {
#pragma unroll
                for (int k2 = 0; k2 < ASLOTS; ++k2) {
                    union { ushort o[8]; uint4 v; } u;
#pragma unroll
                    for (int j = 0; j < 8; ++j) u.o[j] = f2b(xv[k2] * hreg[k2][p][j]);
                    *(uint4*)&As[tb + 32 * k2][teg * 8] = u.v;
                }
            } else if (s == S) {
#pragma unroll
                for (int k2 = 0; k2 < ASLOTS; ++k2) {
                    const float* src = h + (size_t)(b0 + tb + 32 * k2) * 1280
                                         + (size_t)(iw + 1) * E_ + p * 64 + teg * 8;
                    float4 v0 = *(const float4*)(src);
                    float4 v1 = *(const float4*)(src + 4);
                    union { ushort o[8]; uint4 v; } u;
                    u.o[0] = f2b(v0.x); u.o[1] = f2b(v0.y); u.o[2] = f2b(v0.z); u.o[3] = f2b(v0.w);
                    u.o[4] = f2b(v1.x); u.o[5] = f2b(v1.y); u.o[6] = f2b(v1.z); u.o[7] = f2b(v1.w);
                    *(uint4*)&As[tb + 32 * k2][teg * 8] = u.v;
                }
            } else {
                int j0 = (s - S - 1) * 128 + p * 64 + teg * 8;
#pragma unroll
                for (int k2 = 0; k2 < ASLOTS; ++k2) {
                    int b = b0 + tb + 32 * k2;
                    union { ushort o[8]; uint4 v; } u;
#pragma unroll
                    for (int jj = 0; jj < 8; ++jj) {
                        int sp = j0 + jj;
                        u.o[jj] = (sp < S) ? f2b(xT[(size_t)sp * NSAMP + b]) : (ushort)0;
                    }
                    *(uint4*)&As[tb + 32 * k2][teg * 8] = u.v;
                }
            }
#pragma unroll
            for (int slot = tid; slot < BN * 8; slot += 256) {
                int m = slot >> 3, eg2 = slot & 7;
                *(uint4*)&Bs[m][eg2 * 8] =
                    *(const uint4*)(wWb + ((size_t)s * M + m0 + m) * E_ + p * 64 + eg2 * 8);
            }
            __syncthreads();
#pragma unroll
            for (int kk = 0; kk < 2; ++kk) {
                short8 af[SM], bfr[SN];
#pragma unroll
                for (int i = 0; i < SM; ++i)
                    af[i] = *(const short8*)&As[wm0 + i * 16 + lr][kk * 32 + quad * 8];
#pragma unroll
                for (int j = 0; j < SN; ++j)
                    bfr[j] = *(const short8*)&Bs[wn0 + j * 16 + lr][kk * 32 + quad * 8];
#pragma unroll
                for (int i = 0; i < SM; ++i)
#pragma unroll
                    for (int j = 0; j < SN; ++j)
                        acc[i][j] = __builtin_amdgcn_mfma_f32_16x16x32_bf16(af[i], bfr[j], acc[i][j], 0, 0, 0);
            }
            __syncthreads();
        }
    }

    float* dst = partial + (size_t)ks * NSAMP * M;
#pragma unroll
    for (int i = 0; i < SM; ++i)
#pragma unroll
        for (int j = 0; j < SN; ++j)
#pragma unroll
            for (int r = 0; r < 4; ++r) {
                int row = wm0 + i * 16 + quad * 4 + r;
                int col = wn0 + j * 16 + lr;
                dst[(size_t)(b0 + row) * M + m0 + col] = acc[i][j][r];
            }
}

// -------------------- reduce partials + bb (+ReLU), emit xT fp32 for next layer --------------
__global__ void reduce_mid(const float* __restrict__ partial, const float* __restrict__ bb,
                           float* __restrict__ xTn, int KS, int relu)
{
    __shared__ float t[32][33];
    const int b0 = (blockIdx.x >> 3) * 32;
    const int m0 = (blockIdx.x & 7) * 32;
    const int mo = threadIdx.x & 31;
    const int bs0 = threadIdx.x >> 5;   // 0..7
    const float bv = bb[m0 + mo];
#pragma unroll
    for (int r = 0; r < 4; ++r) {
        const int bs = bs0 + 8 * r;
        const size_t off = (size_t)(b0 + bs) * 256 + m0 + mo;
        float a0 = 0.f, a1 = 0.f, a2 = 0.f, a3 = 0.f;
#pragma unroll
        for (int k = 0; k < 16; k += 4) {
            a0 += partial[(size_t)(k + 0) * (NSAMP * 256) + off];
            a1 += partial[(size_t)(k + 1) * (NSAMP * 256) + off];
            a2 += partial[(size_t)(k + 2) * (NSAMP * 256) + off];
            a3 += partial[(size_t)(k + 3) * (NSAMP * 256) + off];
        }
        float a = (a0 + a1) + (a2 + a3) + bv;
        if (relu) a = fmaxf(a, 0.f);
        t[bs][mo] = a;
    }
    __syncthreads();
    const int bo = threadIdx.x & 31;
    const int ms0 = threadIdx.x >> 5;
#pragma unroll
    for (int r = 0; r < 4; ++r) {
        const int ms = ms0 + 8 * r;
        xTn[(size_t)(m0 + ms) * NSAMP + b0 + bo] = t[bo][ms];
    }
}

// -------------------- final layer reduce -> d_out (fp32, ReLU) --------------------
__global__ void reduce_out(const float* __restrict__ partial, const float* __restrict__ bb,
                           float* __restrict__ out, int KS)
{
    int idx = blockIdx.x * 256 + threadIdx.x;   // < 2048*16
    float a0 = 0.f, a1 = 0.f, a2 = 0.f, a3 = 0.f;
#pragma unroll
    for (int k = 0; k < 32; k += 4) {
        a0 += partial[(size_t)(k + 0) * (NSAMP * 16) + idx];
        a1 += partial[(size_t)(k + 1) * (NSAMP * 16) + idx];
        a2 += partial[(size_t)(k + 2) * (NSAMP * 16) + idx];
        a3 += partial[(size_t)(k + 3) * (NSAMP * 16) + idx];
    }
    out[idx] = fmaxf((a0 + a1) + (a2 + a3) + bb[idx & 15], 0.f);
}

extern "C" void kernel_launch(void* const* d_in, const int* in_sizes, int n_in,
                              void* d_out, int out_size, void* d_ws, size_t ws_size,
                              hipStream_t stream)
{
    const float* input = (const float*)d_in[0];
    const float* l1W   = (const float*)d_in[1];
    const float* l1b   = (const float*)d_in[2];

    char* ws = (char*)d_ws;
    // layout (bytes): wWb 16.98M | h 10.49M | xT0 2M | xT1 2M | partial 33.55M = 65.2MB
    ushort* wWb = (ushort*)(ws + 0);
    float* h    = (float*)(ws + 16975872);
    float* xT0  = (float*)(ws + 27461632);
    float* xT1  = (float*)(ws + 29558784);
    float* part = (float*)(ws + 31655936);

    hipLaunchKernelGGL(hyper_h, dim3(2048 * 5), dim3(256), 0, stream, input, l1W, l1b, h);
    hipLaunchKernelGGL(x0_t, dim3(176 * 2048 / 256), dim3(256), 0, stream, input, xT0);

    const int S_[5] = {176, 256, 256, 256, 256};
    const int M_[5] = {256, 256, 256, 256, 16};
    float* xt[2] = {xT0, xT1};

    for (int i = 0; i < 5; ++i) {
        const float* wW = (const float*)d_in[3 + 4 * i];
        const float* wb = (const float*)d_in[4 + 4 * i];
        const float* bW = (const float*)d_in[5 + 4 * i];
        const float* bb = (const float*)d_in[6 + 4 * i];
        float* xin = xt[i & 1];
        int n = S_[i] * M_[i] * E_;
        hipLaunchKernelGGL(cvt_bf16, dim3(n / 2048), dim3(256), 0, stream, wW, wWb, n);
        hipLaunchKernelGGL(cvt_bias, dim3(3 * M_[i] * E_ / 256), dim3(256), 0, stream,
                           bW, wb, wWb, S_[i], M_[i]);

        if (M_[i] == 256) {
            const int btiles = 16, ntiles = 4, ksplit = 16;
            hipLaunchKernelGGL(gemm_big, dim3(btiles * ntiles * ksplit), dim3(256), 0, stream,
                               wWb, h, xin, part, S_[i], 2 * i, ksplit, btiles, ntiles);
            hipLaunchKernelGGL(reduce_mid, dim3(512), dim3(256), 0, stream,
                               part, bb, xt[(i + 1) & 1], ksplit, (i < 3) ? 1 : 0);
        } else {
            const int btiles = 8, ntiles = 1, ksplit = 32;
            hipLaunchKernelGGL((gemm_k<256, 16, 4, 1>), dim3(btiles * ntiles * ksplit), dim3(256), 0, stream,
                               wWb, h, xin, part, S_[i], 16, 2 * i, ksplit, btiles, ntiles);
            hipLaunchKernelGGL(reduce_out, dim3(128), dim3(256), 0, stream,
                               part, bb, (float*)d_out, ksplit);
        }
    }
}

// Round 8
// 637.023 us; speedup vs baseline: 1.2418x; 1.0358x over previous
//
#include <hip/hip_runtime.h>
#include <hip/hip_bf16.h>

#define E_ 128
#define NSAMP 2048

typedef __attribute__((ext_vector_type(8))) short short8;
typedef __attribute__((ext_vector_type(4))) float floatx4;

__device__ __forceinline__ ushort f2b(float f) {
    union { __hip_bfloat16 h; ushort u; } cv;
    cv.h = __float2bfloat16(f);
    return cv.u;
}

__device__ __forceinline__ void gload_lds16(const ushort* g, ushort* l) {
    __builtin_amdgcn_global_load_lds(
        (const __attribute__((address_space(1))) void*)g,
        (__attribute__((address_space(3))) void*)l, 16, 0, 0);
}

// -------------------- h = ReLU(ids @ l1W^T + l1b), fp32 --------------------
__global__ void hyper_h(const float* __restrict__ input, const float* __restrict__ l1W,
                        const float* __restrict__ l1b, float* __restrict__ h)
{
    int b = blockIdx.x / 5;
    int o = (blockIdx.x % 5) * 256 + threadIdx.x;
    const float* ids = input + (size_t)b * 192 + 176;
    const float* w = l1W + (size_t)o * 16;
    float a = l1b[o];
#pragma unroll
    for (int i = 0; i < 16; i += 4) {
        float4 wv = *(const float4*)(w + i);
        a += ids[i] * wv.x + ids[i + 1] * wv.y + ids[i + 2] * wv.z + ids[i + 3] * wv.w;
    }
    h[(size_t)b * 1280 + o] = fmaxf(a, 0.f);
}

// -------------------- xT0[s][b] = input[b][s]  (s < 176), fp32 --------------------
__global__ void x0_t(const float* __restrict__ input, float* __restrict__ xT0)
{
    int idx = blockIdx.x * 256 + threadIdx.x;   // < 176*2048
    int s = idx >> 11, b = idx & 2047;
    xT0[idx] = input[(size_t)b * 192 + s];
}

// -------------------- fp32 -> bf16 convert (wW bulk) --------------------
__global__ void cvt_bf16(const float* __restrict__ src, ushort* __restrict__ dst, int n)
{
    int i = (blockIdx.x * 256 + threadIdx.x) * 8;
    if (i >= n) return;
    float4 a = *(const float4*)(src + i);
    float4 b = *(const float4*)(src + i + 4);
    union { ushort o[8]; uint4 v; } u;
    u.o[0] = f2b(a.x); u.o[1] = f2b(a.y); u.o[2] = f2b(a.z); u.o[3] = f2b(a.w);
    u.o[4] = f2b(b.x); u.o[5] = f2b(b.y); u.o[6] = f2b(b.z); u.o[7] = f2b(b.w);
    *(uint4*)(dst + i) = u.v;
}

// -------------------- build 3 virtual B-slices: [S]=bW rows, [S+1..S+2]=wb^T chunks --------
__global__ void cvt_bias(const float* __restrict__ bW, const float* __restrict__ wb,
                         ushort* __restrict__ dst, int S, int M)
{
    int idx = blockIdx.x * 256 + threadIdx.x;   // < 3*M*E_
    int slice = idx / (M * E_);
    int rem = idx - slice * (M * E_);
    int m = rem / E_, e = rem - m * E_;
    ushort v;
    if (slice == 0) {
        v = f2b(bW[(size_t)m * E_ + e]);
    } else {
        int s = (slice - 1) * 128 + e;
        v = (s < S) ? f2b(wb[(size_t)s * M + m]) : (ushort)0;
    }
    dst[(size_t)(S + slice) * M * E_ + rem] = v;
}

// ==================== big-layer GEMM, reassociated ====================
// G[m][b] = sum_e wWb[s][m][e] * h_bf16[b][e]; acc[m][b] += x[b,s] * G  (x fp32!)
// A-operand: wWb slice (128 m x 128 e) streamed to dbuf LDS via global_load_lds,
//   16B-group XOR swizzle g' = (g&8)|((g&7)^(r&7)).
// B-operand: h fragments FIXED in registers (loaded once; no A staging at all).
// One barrier per slice; it drains a DMA issued a full slice (~2000cyc) earlier.
// xv loads issued BEFORE the DMA so their waitcnt doesn't drain the DMA queue.
// Block tile 128 m x 128 b; 4 waves 2x2 (64x64); ksplit=16 -> grid 512, 2 blk/CU.
__global__ __launch_bounds__(256, 2) void gemm_big2(
    const ushort* __restrict__ wWb, const float* __restrict__ h,
    const float* __restrict__ xT, float* __restrict__ partial,
    int S, int iw, int ksplit)
{
    __shared__ ushort Ws[2][128 * 128];

    const int tid = threadIdx.x;
    const int mt = blockIdx.x & 1;
    const int bt = (blockIdx.x >> 1) & 15;
    const int ks = blockIdx.x >> 5;
    const int m0 = mt * 128;
    const int b0 = bt * 128;
    const int total_s = S + 3;
    const int base = total_s / ksplit;
    const int rem = total_s - base * ksplit;
    const int s0 = ks * base + min(ks, rem);
    const int s1 = s0 + base + (ks < rem ? 1 : 0);
    const int sm = min(s1, S);      // bias slices (>=S) handled at tail

    const int lane = tid & 63;
    const int wave = tid >> 6;
    const int quad = lane >> 4;
    const int lr = lane & 15;
    const int wm = (wave >> 1) * 64;    // wave m-offset
    const int wb_ = (wave & 1) * 64;    // wave b-offset

    const int dr = lane >> 4;           // DMA row within 4-row group
    const int dg = lane & 15;           // DMA LDS slot group

    // ---- prologue: DMA slice s0 -> buf 0 (flies across h-frag loading) ----
#pragma unroll
    for (int t = 0; t < 8; ++t) {
        int rbase = (wave * 8 + t) * 4;
        int r = rbase + dr;
        int g = (dg & 8) | ((dg & 7) ^ (r & 7));
        gload_lds16(wWb + ((size_t)s0 * 256 + m0 + r) * 128 + g * 8,
                    &Ws[0][rbase * 128 + lane * 8]);
    }

    // ---- fixed h-frags (B-operand) ----
    short8 hf[4][4];
#pragma unroll
    for (int j = 0; j < 4; ++j) {
        const float* hr = h + (size_t)(b0 + wb_ + j * 16 + lr) * 1280 + (size_t)iw * E_;
#pragma unroll
        for (int kk = 0; kk < 4; ++kk) {
            float4 v0 = *(const float4*)(hr + kk * 32 + quad * 8);
            float4 v1 = *(const float4*)(hr + kk * 32 + quad * 8 + 4);
            union { ushort o[8]; short8 v; } u;
            u.o[0] = f2b(v0.x); u.o[1] = f2b(v0.y); u.o[2] = f2b(v0.z); u.o[3] = f2b(v0.w);
            u.o[4] = f2b(v1.x); u.o[5] = f2b(v1.y); u.o[6] = f2b(v1.z); u.o[7] = f2b(v1.w);
            hf[j][kk] = u.v;
        }
    }

    floatx4 acc[4][4];
#pragma unroll
    for (int i = 0; i < 4; ++i)
#pragma unroll
        for (int j = 0; j < 4; ++j)
            acc[i][j] = (floatx4){0.f, 0.f, 0.f, 0.f};

    const floatx4 zf = (floatx4){0.f, 0.f, 0.f, 0.f};

    int cur = 0;
    for (int s = s0; s < sm; ++s) {
        // xv loads FIRST (before DMA) so their waitcnt can leave the DMA in flight
        float xv[4];
#pragma unroll
        for (int j = 0; j < 4; ++j)
            xv[j] = xT[(size_t)s * NSAMP + b0 + wb_ + j * 16 + lr];

        __syncthreads();   // drains DMA for buf[cur] (issued one full slice ago)

        if (s + 1 < sm) {
#pragma unroll
            for (int t = 0; t < 8; ++t) {
                int rbase = (wave * 8 + t) * 4;
                int r = rbase + dr;
                int g = (dg & 8) | ((dg & 7) ^ (r & 7));
                gload_lds16(wWb + ((size_t)(s + 1) * 256 + m0 + r) * 128 + g * 8,
                            &Ws[cur ^ 1][rbase * 128 + lane * 8]);
            }
        }

#pragma unroll
        for (int i = 0; i < 4; ++i) {
            const int r = wm + i * 16 + lr;
            short8 af[4];
#pragma unroll
            for (int kk = 0; kk < 4; ++kk) {
                int g = kk * 4 + quad;
                int g2 = (g & 8) | ((g & 7) ^ (r & 7));
                af[kk] = *(const short8*)&Ws[cur][r * 128 + g2 * 8];
            }
            floatx4 Gj[4];
#pragma unroll
            for (int j = 0; j < 4; ++j)
                Gj[j] = __builtin_amdgcn_mfma_f32_16x16x32_bf16(af[0], hf[j][0], zf, 0, 0, 0);
#pragma unroll
            for (int kk = 1; kk < 4; ++kk)
#pragma unroll
                for (int j = 0; j < 4; ++j)
                    Gj[j] = __builtin_amdgcn_mfma_f32_16x16x32_bf16(af[kk], hf[j][kk], Gj[j], 0, 0, 0);
#pragma unroll
            for (int j = 0; j < 4; ++j)
                acc[i][j] += xv[j] * Gj[j];
        }
        cur ^= 1;
    }

    // ---- bias slices (<=3): s==S -> B = h chunk iw+1; s>S -> B = gathered x ----
    for (int s = sm; s < s1; ++s) {
        __syncthreads();
#pragma unroll
        for (int t = 0; t < 8; ++t) {
            int rbase = (wave * 8 + t) * 4;
            int r = rbase + dr;
            int g = (dg & 8) | ((dg & 7) ^ (r & 7));
            gload_lds16(wWb + ((size_t)s * 256 + m0 + r) * 128 + g * 8,
                        &Ws[0][rbase * 128 + lane * 8]);
        }
        short8 bfb[4][4];
        if (s == S) {
#pragma unroll
            for (int j = 0; j < 4; ++j) {
                const float* hr = h + (size_t)(b0 + wb_ + j * 16 + lr) * 1280 + (size_t)(iw + 1) * E_;
#pragma unroll
                for (int kk = 0; kk < 4; ++kk) {
                    float4 v0 = *(const float4*)(hr + kk * 32 + quad * 8);
                    float4 v1 = *(const float4*)(hr + kk * 32 + quad * 8 + 4);
                    union { ushort o[8]; short8 v; } u;
                    u.o[0] = f2b(v0.x); u.o[1] = f2b(v0.y); u.o[2] = f2b(v0.z); u.o[3] = f2b(v0.w);
                    u.o[4] = f2b(v1.x); u.o[5] = f2b(v1.y); u.o[6] = f2b(v1.z); u.o[7] = f2b(v1.w);
                    bfb[j][kk] = u.v;
                }
            }
        } else {
            int off = (s - S - 1) * 128;
#pragma unroll
            for (int j = 0; j < 4; ++j) {
                int b = b0 + wb_ + j * 16 + lr;
#pragma unroll
                for (int kk = 0; kk < 4; ++kk) {
                    union { ushort o[8]; short8 v; } u;
#pragma unroll
                    for (int t = 0; t < 8; ++t) {
                        int sp = off + kk * 32 + quad * 8 + t;
                        u.o[t] = (sp < S) ? f2b(xT[(size_t)sp * NSAMP + b]) : (ushort)0;
                    }
                    bfb[j][kk] = u.v;
                }
            }
        }
        __syncthreads();   // drains this slice's DMA (immediate; <=3 times)
#pragma unroll
        for (int i = 0; i < 4; ++i) {
            const int r = wm + i * 16 + lr;
            short8 af[4];
#pragma unroll
            for (int kk = 0; kk < 4; ++kk) {
                int g = kk * 4 + quad;
                int g2 = (g & 8) | ((g & 7) ^ (r & 7));
                af[kk] = *(const short8*)&Ws[0][r * 128 + g2 * 8];
            }
            floatx4 Gj[4];
#pragma unroll
            for (int j = 0; j < 4; ++j)
                Gj[j] = __builtin_amdgcn_mfma_f32_16x16x32_bf16(af[0], bfb[j][0], zf, 0, 0, 0);
#pragma unroll
            for (int kk = 1; kk < 4; ++kk)
#pragma unroll
                for (int j = 0; j < 4; ++j)
                    Gj[j] = __builtin_amdgcn_mfma_f32_16x16x32_bf16(af[kk], bfb[j][kk], Gj[j], 0, 0, 0);
#pragma unroll
            for (int j = 0; j < 4; ++j)
                acc[i][j] += Gj[j];
        }
    }

    // ---- epilogue: D rows = m, cols = b; partial layout [ks][m][b] ----
    float* dst = partial + (size_t)ks * (256 * NSAMP);
#pragma unroll
    for (int i = 0; i < 4; ++i)
#pragma unroll
        for (int j = 0; j < 4; ++j)
#pragma unroll
            for (int r = 0; r < 4; ++r) {
                int m = m0 + wm + i * 16 + quad * 4 + r;
                int b = b0 + wb_ + j * 16 + lr;
                dst[(size_t)m * NSAMP + b] = acc[i][j][r];
            }
}

// ==================== small-layer GEMM (M=16) — unchanged, partial [ks][b][m] ==========
template<int BM, int BN, int WROWS, int WCOLS>
__global__ __launch_bounds__(256, 2) void gemm_k(
    const ushort* __restrict__ wWb, const float* __restrict__ h,
    const float* __restrict__ xT, float* __restrict__ partial,
    int S, int M, int iw, int ksplit, int btiles, int ntiles)
{
    constexpr int SM = BM / WROWS / 16;
    constexpr int SN = BN / WCOLS / 16;
    constexpr int ASLOTS = BM * 8 / 256;
    constexpr int LDA = 72;

    __shared__ ushort As[BM][LDA];
    __shared__ ushort Bs[BN][LDA];

    const int tid = threadIdx.x;
    const int bt = blockIdx.x % btiles;
    const int nt = (blockIdx.x / btiles) % ntiles;
    const int ks = blockIdx.x / (btiles * ntiles);
    const int b0 = bt * BM;
    const int m0 = nt * BN;
    const int total_s = S + 3;
    const int base = total_s / ksplit;
    const int rem = total_s - base * ksplit;
    const int s0 = ks * base + min(ks, rem);
    const int s1 = s0 + base + (ks < rem ? 1 : 0);

    const int lane = tid & 63;
    const int wave = tid >> 6;
    const int quad = lane >> 4;
    const int lr = lane & 15;
    const int wm0 = (wave / WCOLS) * (BM / WROWS);
    const int wn0 = (wave % WCOLS) * (BN / WCOLS);

    const int tb = tid >> 3;
    const int teg = tid & 7;

    float hreg[ASLOTS][2][8];
#pragma unroll
    for (int k2 = 0; k2 < ASLOTS; ++k2) {
        int b = tb + 32 * k2;
#pragma unroll
        for (int p = 0; p < 2; ++p) {
            const float* src = h + (size_t)(b0 + b) * 1280 + (size_t)iw * E_ + p * 64 + teg * 8;
            float4 v0 = *(const float4*)(src);
            float4 v1 = *(const float4*)(src + 4);
            hreg[k2][p][0] = v0.x; hreg[k2][p][1] = v0.y; hreg[k2][p][2] = v0.z; hreg[k2][p][3] = v0.w;
            hreg[k2][p][4] = v1.x; hreg[k2][p][5] = v1.y; hreg[k2][p][6] = v1.z; hreg[k2][p][7] = v1.w;
        }
    }

    floatx4 acc[SM][SN];
#pragma unroll
    for (int i = 0; i < SM; ++i)
#pragma unroll
        for (int j = 0; j < SN; ++j)
            acc[i][j] = (floatx4){0.f, 0.f, 0.f, 0.f};

    for (int s = s0; s < s1; ++s) {
        float xv[ASLOTS];
        if (s < S) {
#pragma unroll
            for (int k2 = 0; k2 < ASLOTS; ++k2)
                xv[k2] = xT[(size_t)s * NSAMP + b0 + tb + 32 * k2];
        }

#pragma unroll
        for (int p = 0; p < 2; ++p) {
            if (s < S) {
#pragma unroll
                for (int k2 = 0; k2 < ASLOTS; ++k2) {
                    union { ushort o[8]; uint4 v; } u;
#pragma unroll
                    for (int j = 0; j < 8; ++j) u.o[j] = f2b(xv[k2] * hreg[k2][p][j]);
                    *(uint4*)&As[tb + 32 * k2][teg * 8] = u.v;
                }
            } else if (s == S) {
#pragma unroll
                for (int k2 = 0; k2 < ASLOTS; ++k2) {
                    const float* src = h + (size_t)(b0 + tb + 32 * k2) * 1280
                                         + (size_t)(iw + 1) * E_ + p * 64 + teg * 8;
                    float4 v0 = *(const float4*)(src);
                    float4 v1 = *(const float4*)(src + 4);
                    union { ushort o[8]; uint4 v; } u;
                    u.o[0] = f2b(v0.x); u.o[1] = f2b(v0.y); u.o[2] = f2b(v0.z); u.o[3] = f2b(v0.w);
                    u.o[4] = f2b(v1.x); u.o[5] = f2b(v1.y); u.o[6] = f2b(v1.z); u.o[7] = f2b(v1.w);
                    *(uint4*)&As[tb + 32 * k2][teg * 8] = u.v;
                }
            } else {
                int j0 = (s - S - 1) * 128 + p * 64 + teg * 8;
#pragma unroll
                for (int k2 = 0; k2 < ASLOTS; ++k2) {
                    int b = b0 + tb + 32 * k2;
                    union { ushort o[8]; uint4 v; } u;
#pragma unroll
                    for (int jj = 0; jj < 8; ++jj) {
                        int sp = j0 + jj;
                        u.o[jj] = (sp < S) ? f2b(xT[(size_t)sp * NSAMP + b]) : (ushort)0;
                    }
                    *(uint4*)&As[tb + 32 * k2][teg * 8] = u.v;
                }
            }
#pragma unroll
            for (int slot = tid; slot < BN * 8; slot += 256) {
                int m = slot >> 3, eg2 = slot & 7;
                *(uint4*)&Bs[m][eg2 * 8] =
                    *(const uint4*)(wWb + ((size_t)s * M + m0 + m) * E_ + p * 64 + eg2 * 8);
            }
            __syncthreads();
#pragma unroll
            for (int kk = 0; kk < 2; ++kk) {
                short8 af[SM], bfr[SN];
#pragma unroll
                for (int i = 0; i < SM; ++i)
                    af[i] = *(const short8*)&As[wm0 + i * 16 + lr][kk * 32 + quad * 8];
#pragma unroll
                for (int j = 0; j < SN; ++j)
                    bfr[j] = *(const short8*)&Bs[wn0 + j * 16 + lr][kk * 32 + quad * 8];
#pragma unroll
                for (int i = 0; i < SM; ++i)
#pragma unroll
                    for (int j = 0; j < SN; ++j)
                        acc[i][j] = __builtin_amdgcn_mfma_f32_16x16x32_bf16(af[i], bfr[j], acc[i][j], 0, 0, 0);
            }
            __syncthreads();
        }
    }

    float* dst = partial + (size_t)ks * NSAMP * M;
#pragma unroll
    for (int i = 0; i < SM; ++i)
#pragma unroll
        for (int j = 0; j < SN; ++j)
#pragma unroll
            for (int r = 0; r < 4; ++r) {
                int row = wm0 + i * 16 + quad * 4 + r;
                int col = wn0 + j * 16 + lr;
                dst[(size_t)(b0 + row) * M + m0 + col] = acc[i][j][r];
            }
}

// ---------- reduce partials [ks][m][b] + bb (+ReLU) -> xT [m][b], vectorized ----------
__global__ void reduce_mid(const float* __restrict__ partial, const float* __restrict__ bb,
                           float* __restrict__ xTn, int KS, int relu)
{
    int idx = (blockIdx.x * 256 + threadIdx.x) * 4;   // grid 512 covers 256*2048 floats
    int m = idx >> 11;
    floatx4 a0 = {0.f,0.f,0.f,0.f}, a1 = a0, a2 = a0, a3 = a0;
#pragma unroll 4
    for (int k = 0; k < KS; k += 4) {
        a0 += *(const floatx4*)&partial[(size_t)(k + 0) * (256 * NSAMP) + idx];
        a1 += *(const floatx4*)&partial[(size_t)(k + 1) * (256 * NSAMP) + idx];
        a2 += *(const floatx4*)&partial[(size_t)(k + 2) * (256 * NSAMP) + idx];
        a3 += *(const floatx4*)&partial[(size_t)(k + 3) * (256 * NSAMP) + idx];
    }
    floatx4 r = (a0 + a1) + (a2 + a3) + bb[m];
    if (relu) {
        r[0] = fmaxf(r[0], 0.f); r[1] = fmaxf(r[1], 0.f);
        r[2] = fmaxf(r[2], 0.f); r[3] = fmaxf(r[3], 0.f);
    }
    *(floatx4*)&xTn[idx] = r;
}

// -------------------- final layer reduce (partial [ks][b][m]) -> d_out --------------------
__global__ void reduce_out(const float* __restrict__ partial, const float* __restrict__ bb,
                           float* __restrict__ out, int KS)
{
    int idx = blockIdx.x * 256 + threadIdx.x;   // < 2048*16
    float a0 = 0.f, a1 = 0.f, a2 = 0.f, a3 = 0.f;
#pragma unroll
    for (int k = 0; k < 32; k += 4) {
        a0 += partial[(size_t)(k + 0) * (NSAMP * 16) + idx];
        a1 += partial[(size_t)(k + 1) * (NSAMP * 16) + idx];
        a2 += partial[(size_t)(k + 2) * (NSAMP * 16) + idx];
        a3 += partial[(size_t)(k + 3) * (NSAMP * 16) + idx];
    }
    out[idx] = fmaxf((a0 + a1) + (a2 + a3) + bb[idx & 15], 0.f);
}

extern "C" void kernel_launch(void* const* d_in, const int* in_sizes, int n_in,
                              void* d_out, int out_size, void* d_ws, size_t ws_size,
                              hipStream_t stream)
{
    const float* input = (const float*)d_in[0];
    const float* l1W   = (const float*)d_in[1];
    const float* l1b   = (const float*)d_in[2];

    char* ws = (char*)d_ws;
    ushort* wWb = (ushort*)(ws + 0);
    float* h    = (float*)(ws + 16975872);
    float* xT0  = (float*)(ws + 27461632);
    float* xT1  = (float*)(ws + 29558784);
    float* part = (float*)(ws + 31655936);

    hipLaunchKernelGGL(hyper_h, dim3(2048 * 5), dim3(256), 0, stream, input, l1W, l1b, h);
    hipLaunchKernelGGL(x0_t, dim3(176 * 2048 / 256), dim3(256), 0, stream, input, xT0);

    const int S_[5] = {176, 256, 256, 256, 256};
    const int M_[5] = {256, 256, 256, 256, 16};
    float* xt[2] = {xT0, xT1};

    for (int i = 0; i < 5; ++i) {
        const float* wW = (const float*)d_in[3 + 4 * i];
        const float* wb = (const float*)d_in[4 + 4 * i];
        const float* bW = (const float*)d_in[5 + 4 * i];
        const float* bb = (const float*)d_in[6 + 4 * i];
        float* xin = xt[i & 1];
        int n = S_[i] * M_[i] * E_;
        hipLaunchKernelGGL(cvt_bf16, dim3(n / 2048), dim3(256), 0, stream, wW, wWb, n);
        hipLaunchKernelGGL(cvt_bias, dim3(3 * M_[i] * E_ / 256), dim3(256), 0, stream,
                           bW, wb, wWb, S_[i], M_[i]);

        if (M_[i] == 256) {
            hipLaunchKernelGGL(gemm_big2, dim3(512), dim3(256), 0, stream,
                               wWb, h, xin, part, S_[i], 2 * i, 16);
            hipLaunchKernelGGL(reduce_mid, dim3(512), dim3(256), 0, stream,
                               part, bb, xt[(i + 1) & 1], 16, (i < 3) ? 1 : 0);
        } else {
            const int btiles = 8, ntiles = 1, ksplit = 32;
            hipLaunchKernelGGL((gemm_k<256, 16, 4, 1>), dim3(btiles * ntiles * ksplit), dim3(256), 0, stream,
                               wWb, h, xin, part, S_[i], 16, 2 * i, ksplit, btiles, ntiles);
            hipLaunchKernelGGL(reduce_out, dim3(128), dim3(256), 0, stream,
                               part, bb, (float*)d_out, ksplit);
        }
    }
}